// Round 1
// baseline (1724.260 us; speedup 1.0000x reference)
//
#include <hip/hip_runtime.h>

#define NEG 0.2f

// ---- workspace layout (in floats) ----
#define OFF_PRE   0ull
#define SZ_PRE    (25000ull*640ull)          // pre: [n][0:256)=ni part, [256:512)=nj part, [512:640)=msg part
#define OFF_BCAT  (OFF_PRE + SZ_PRE)
#define SZ_BCAT   (128ull*640ull)
#define OFF_BTOT  (OFF_BCAT + SZ_BCAT)
#define SZ_BTOT   256ull
#define OFF_LOG   (OFF_BTOT + SZ_BTOT)       // logits then ex (overwritten)
#define SZ_LOG    (2ull*400000ull)
#define OFF_MAX   (OFF_LOG + SZ_LOG)         // unsigned max-keys
#define SZ_MAX    (2ull*25000ull)
#define OFF_DEN   (OFF_MAX + SZ_MAX)
#define SZ_DEN    (2ull*25000ull)
#define OFF_AGG   (OFF_DEN + SZ_DEN)
#define SZ_AGG    (25000ull*128ull)

__device__ __forceinline__ unsigned fkey(float f) {
    unsigned u = __float_as_uint(f);
    return (u & 0x80000000u) ? ~u : (u | 0x80000000u);
}
__device__ __forceinline__ float keyf(unsigned k) {
    unsigned u = (k & 0x80000000u) ? (k & 0x7fffffffu) : ~k;
    return __uint_as_float(u);
}

// ---- K0: concat weights for node-pre GEMM; total bias ----
__global__ void k_prep(const float* __restrict__ niW, const float* __restrict__ njW,
                       const float* __restrict__ msgW,
                       const float* __restrict__ nib, const float* __restrict__ njb,
                       const float* __restrict__ eb,
                       float* __restrict__ bcat, float* __restrict__ btot) {
    int idx = blockIdx.x * 256 + threadIdx.x;
    if (idx < 128 * 640) {
        int k = idx / 640, c = idx % 640;
        float v = (c < 256) ? niW[k * 256 + c]
                : (c < 512) ? njW[k * 256 + (c - 256)]
                            : msgW[k * 128 + (c - 512)];
        bcat[idx] = v;
    }
    if (blockIdx.x == 0 && threadIdx.x < 256) {
        int c = threadIdx.x;
        btot[c] = nib[c] + njb[c] + eb[c];
    }
}

// shared inner GEMM tile: acc[4][8] += A[4 rows][64 k] * B[64 k][8 cols]
__device__ __forceinline__ void gemm_tile(const float* Al, int astride, int acol0,
                                          const float* Bl, int trow, int tcol,
                                          float acc[4][8]) {
    for (int k4 = 0; k4 < 64; k4 += 4) {
        float ar[4][4];
#pragma unroll
        for (int r = 0; r < 4; ++r)
            *(float4*)ar[r] = *(const float4*)&Al[(trow * 4 + r) * astride + acol0 + k4];
#pragma unroll
        for (int kk = 0; kk < 4; ++kk) {
            float4 b0 = *(const float4*)&Bl[(k4 + kk) * 128 + tcol * 8];
            float4 b1 = *(const float4*)&Bl[(k4 + kk) * 128 + tcol * 8 + 4];
            float bv[8] = {b0.x, b0.y, b0.z, b0.w, b1.x, b1.y, b1.z, b1.w};
#pragma unroll
            for (int r = 0; r < 4; ++r) {
                float av = ar[r][kk];
#pragma unroll
                for (int j = 0; j < 8; ++j) acc[r][j] = fmaf(av, bv[j], acc[r][j]);
            }
        }
    }
}

// ---- K1: pre = node_features @ bcat   [25000,128]@[128,640] ----
__global__ __launch_bounds__(256) void k_node_pre(const float* __restrict__ nf,
                                                  const float* __restrict__ bcat,
                                                  float* __restrict__ pre) {
    __shared__ float Al[64 * 128];
    __shared__ float Bl[64 * 128];
    int t = threadIdx.x, n0 = blockIdx.x * 64;
    int trow = t >> 4, tcol = t & 15;
#pragma unroll
    for (int q = 0; q < 8; ++q) {
        int g = t + 256 * q;
        int i = g >> 5, k4 = (g & 31) * 4;
        int n = n0 + i;
        float4 v = make_float4(0.f, 0.f, 0.f, 0.f);
        if (n < 25000) v = *(const float4*)&nf[(size_t)n * 128 + k4];
        *(float4*)&Al[i * 128 + k4] = v;
    }
    for (int cc = 0; cc < 5; ++cc) {
        float acc[4][8] = {};
        for (int kh = 0; kh < 2; ++kh) {
            __syncthreads();
#pragma unroll
            for (int q = 0; q < 8; ++q) {
                int g = t + 256 * q;
                int k = g >> 5, c4 = (g & 31) * 4;
                *(float4*)&Bl[k * 128 + c4] =
                    *(const float4*)&bcat[(kh * 64 + k) * 640 + cc * 128 + c4];
            }
            __syncthreads();
            gemm_tile(Al, 128, kh * 64, Bl, trow, tcol, acc);
        }
#pragma unroll
        for (int r = 0; r < 4; ++r) {
            int n = n0 + trow * 4 + r;
            if (n < 25000) {
                *(float4*)&pre[(size_t)n * 640 + cc * 128 + tcol * 8] =
                    make_float4(acc[r][0], acc[r][1], acc[r][2], acc[r][3]);
                *(float4*)&pre[(size_t)n * 640 + cc * 128 + tcol * 8 + 4] =
                    make_float4(acc[r][4], acc[r][5], acc[r][6], acc[r][7]);
            }
        }
        __syncthreads();
    }
}

// ---- K2: edge logits + atomic max ----
__global__ __launch_bounds__(256) void k_edge_logits(
        const float* __restrict__ ef, const int* __restrict__ eidx,
        const float* __restrict__ eW, const float* __restrict__ pre,
        const float* __restrict__ btot, const float* __restrict__ aproj,
        float* __restrict__ logits, unsigned* __restrict__ maxkey) {
    __shared__ float Al[64 * 68];
    __shared__ float Bl[64 * 128];
    __shared__ int dstl[64], srcl[64];
    int t = threadIdx.x, e0 = blockIdx.x * 64;
    int trow = t >> 4, tcol = t & 15;
#pragma unroll
    for (int q = 0; q < 4; ++q) {
        int g = t + 256 * q;
        int e = g >> 4, k4 = (g & 15) * 4;
        *(float4*)&Al[e * 68 + k4] = *(const float4*)&ef[(size_t)(e0 + e) * 64 + k4];
    }
    if (t < 64) { dstl[t] = eidx[e0 + t]; srcl[t] = eidx[400000 + e0 + t]; }
    for (int h = 0; h < 2; ++h) {
        __syncthreads();
#pragma unroll
        for (int q = 0; q < 8; ++q) {
            int g = t + 256 * q;
            int k = g >> 5, c4 = (g & 31) * 4;
            *(float4*)&Bl[k * 128 + c4] = *(const float4*)&eW[k * 256 + h * 128 + c4];
        }
        __syncthreads();
        float acc[4][8] = {};
        gemm_tile(Al, 68, 0, Bl, trow, tcol, acc);

        float bt[8], ap[8];
        *(float4*)bt = *(const float4*)&btot[h * 128 + tcol * 8];
        *(float4*)(bt + 4) = *(const float4*)&btot[h * 128 + tcol * 8 + 4];
        *(float4*)ap = *(const float4*)&aproj[h * 128 + tcol * 8];
        *(float4*)(ap + 4) = *(const float4*)&aproj[h * 128 + tcol * 8 + 4];
#pragma unroll
        for (int r = 0; r < 4; ++r) {
            int e = trow * 4 + r;
            int ed = dstl[e], es = srcl[e];
            float pi[8], pj[8];
            *(float4*)pi = *(const float4*)&pre[(size_t)ed * 640 + h * 128 + tcol * 8];
            *(float4*)(pi + 4) = *(const float4*)&pre[(size_t)ed * 640 + h * 128 + tcol * 8 + 4];
            *(float4*)pj = *(const float4*)&pre[(size_t)es * 640 + 256 + h * 128 + tcol * 8];
            *(float4*)(pj + 4) = *(const float4*)&pre[(size_t)es * 640 + 256 + h * 128 + tcol * 8 + 4];
            float p = 0.f;
#pragma unroll
            for (int j = 0; j < 8; ++j) {
                float hid = acc[r][j] + pi[j] + pj[j] + bt[j];
                hid = hid >= 0.f ? hid : NEG * hid;
                p = fmaf(hid, ap[j], p);
            }
            p += __shfl_xor(p, 1);
            p += __shfl_xor(p, 2);
            p += __shfl_xor(p, 4);
            p += __shfl_xor(p, 8);
            if (tcol == 0) {
                logits[(size_t)(e0 + e) * 2 + h] = p;
                atomicMax(&maxkey[ed * 2 + h], fkey(p));
            }
        }
    }
}

// ---- K3: ex = exp(logit - max); denom += ex ----
__global__ void k_soft(const int* __restrict__ eidx, float* __restrict__ logits,
                       const unsigned* __restrict__ maxkey, float* __restrict__ denom) {
    int idx = blockIdx.x * 256 + threadIdx.x;
    if (idx >= 800000) return;
    int e = idx >> 1, h = idx & 1;
    int ed = eidx[e];
    float m = keyf(maxkey[ed * 2 + h]);
    float ex = __expf(logits[idx] - m);
    logits[idx] = ex;
    atomicAdd(&denom[ed * 2 + h], ex);
}

// ---- K4: messages + attn-weighted scatter add ----
__global__ __launch_bounds__(256) void k_messages(
        const float* __restrict__ ef, const int* __restrict__ eidx,
        const float* __restrict__ msgWb, const float* __restrict__ pre,
        const float* __restrict__ exbuf, const float* __restrict__ denom,
        float* __restrict__ agg) {
    __shared__ float Al[64 * 68];
    __shared__ float Bl[64 * 128];
    __shared__ int dstl[64], srcl[64];
    int t = threadIdx.x, e0 = blockIdx.x * 64;
    int trow = t >> 4, tcol = t & 15;
#pragma unroll
    for (int q = 0; q < 4; ++q) {
        int g = t + 256 * q;
        int e = g >> 4, k4 = (g & 15) * 4;
        *(float4*)&Al[e * 68 + k4] = *(const float4*)&ef[(size_t)(e0 + e) * 64 + k4];
    }
#pragma unroll
    for (int q = 0; q < 8; ++q) {
        int g = t + 256 * q;
        int k = g >> 5, c4 = (g & 31) * 4;
        *(float4*)&Bl[k * 128 + c4] = *(const float4*)&msgWb[k * 128 + c4];
    }
    if (t < 64) { dstl[t] = eidx[e0 + t]; srcl[t] = eidx[400000 + e0 + t]; }
    __syncthreads();
    float acc[4][8] = {};
    gemm_tile(Al, 68, 0, Bl, trow, tcol, acc);

    int h = tcol >> 3;
#pragma unroll
    for (int r = 0; r < 4; ++r) {
        int e = trow * 4 + r;
        int ed = dstl[e], es = srcl[e];
        float pm[8];
        *(float4*)pm = *(const float4*)&pre[(size_t)es * 640 + 512 + tcol * 8];
        *(float4*)(pm + 4) = *(const float4*)&pre[(size_t)es * 640 + 512 + tcol * 8 + 4];
        float attn = exbuf[(size_t)(e0 + e) * 2 + h] / denom[ed * 2 + h];
#pragma unroll
        for (int j = 0; j < 8; ++j) {
            atomicAdd(&agg[(size_t)ed * 128 + tcol * 8 + j], attn * (acc[r][j] + pm[j]));
        }
    }
}

// ---- K5: out = (agg + msg_b*[has_edges]) @ out_W + out_b ----
__global__ __launch_bounds__(256) void k_out(
        const float* __restrict__ agg, const float* __restrict__ denom,
        const float* __restrict__ msgb, const float* __restrict__ outW,
        const float* __restrict__ outb, float* __restrict__ out) {
    __shared__ float Al[64 * 128];
    __shared__ float Bl[64 * 128];
    int t = threadIdx.x, n0 = blockIdx.x * 64;
    int trow = t >> 4, tcol = t & 15;
#pragma unroll
    for (int q = 0; q < 8; ++q) {
        int g = t + 256 * q;
        int i = g >> 5, k4 = (g & 31) * 4;
        int n = n0 + i;
        float4 v = make_float4(0.f, 0.f, 0.f, 0.f);
        if (n < 25000) {
            v = *(const float4*)&agg[(size_t)n * 128 + k4];
            if (denom[n * 2 + (k4 >> 6)] > 0.f) {
                float4 mb = *(const float4*)&msgb[k4];
                v.x += mb.x; v.y += mb.y; v.z += mb.z; v.w += mb.w;
            }
        }
        *(float4*)&Al[i * 128 + k4] = v;
    }
    float acc[4][8] = {};
    for (int kh = 0; kh < 2; ++kh) {
        __syncthreads();
#pragma unroll
        for (int q = 0; q < 8; ++q) {
            int g = t + 256 * q;
            int k = g >> 5, c4 = (g & 31) * 4;
            *(float4*)&Bl[k * 128 + c4] = *(const float4*)&outW[(kh * 64 + k) * 128 + c4];
        }
        __syncthreads();
        gemm_tile(Al, 128, kh * 64, Bl, trow, tcol, acc);
    }
    float ob[8];
    *(float4*)ob = *(const float4*)&outb[tcol * 8];
    *(float4*)(ob + 4) = *(const float4*)&outb[tcol * 8 + 4];
#pragma unroll
    for (int r = 0; r < 4; ++r) {
        int n = n0 + trow * 4 + r;
        if (n < 25000) {
            *(float4*)&out[(size_t)n * 128 + tcol * 8] =
                make_float4(acc[r][0] + ob[0], acc[r][1] + ob[1], acc[r][2] + ob[2], acc[r][3] + ob[3]);
            *(float4*)&out[(size_t)n * 128 + tcol * 8 + 4] =
                make_float4(acc[r][4] + ob[4], acc[r][5] + ob[5], acc[r][6] + ob[6], acc[r][7] + ob[7]);
        }
    }
}

extern "C" void kernel_launch(void* const* d_in, const int* in_sizes, int n_in,
                              void* d_out, int out_size, void* d_ws, size_t ws_size,
                              hipStream_t stream) {
    const float* nf    = (const float*)d_in[0];
    const float* ef    = (const float*)d_in[1];
    const int*   eidx  = (const int*)d_in[2];
    const float* niW   = (const float*)d_in[3];
    const float* nib   = (const float*)d_in[4];
    const float* njW   = (const float*)d_in[5];
    const float* njb   = (const float*)d_in[6];
    const float* eW    = (const float*)d_in[7];
    const float* eb    = (const float*)d_in[8];
    const float* aproj = (const float*)d_in[9];
    const float* msgW  = (const float*)d_in[10];
    const float* msgb  = (const float*)d_in[11];
    const float* outW  = (const float*)d_in[12];
    const float* outb  = (const float*)d_in[13];

    float* ws = (float*)d_ws;
    float* pre      = ws + OFF_PRE;
    float* bcat     = ws + OFF_BCAT;
    float* btot     = ws + OFF_BTOT;
    float* logits   = ws + OFF_LOG;
    unsigned* maxkey = (unsigned*)(ws + OFF_MAX);
    float* denom    = ws + OFF_DEN;
    float* agg      = ws + OFF_AGG;

    // zero maxkey + denom + agg (contiguous)
    hipMemsetAsync(ws + OFF_MAX, 0, (size_t)(SZ_MAX + SZ_DEN + SZ_AGG) * 4, stream);

    k_prep<<<320, 256, 0, stream>>>(niW, njW, msgW, nib, njb, eb, bcat, btot);
    k_node_pre<<<391, 256, 0, stream>>>(nf, bcat, pre);
    k_edge_logits<<<6250, 256, 0, stream>>>(ef, eidx, eW, pre, btot, aproj, logits, maxkey);
    k_soft<<<3125, 256, 0, stream>>>(eidx, logits, maxkey, denom);
    k_messages<<<6250, 256, 0, stream>>>(ef, eidx, msgW + 128 * 128, pre, logits, denom, agg);
    k_out<<<391, 256, 0, stream>>>(agg, denom, msgb, outW, outb, (float*)d_out);
}

// Round 2
// 500.870 us; speedup vs baseline: 3.4425x; 3.4425x over previous
//
#include <hip/hip_runtime.h>

#define NEG 0.2f

// ---- workspace layout (in floats) ----
#define OFF_PRE   0ull
#define SZ_PRE    (25000ull*640ull)          // pre: [n][0:256)=ni, [256:512)=nj, [512:640)=msg part
#define OFF_BCAT  (OFF_PRE + SZ_PRE)
#define SZ_BCAT   (128ull*640ull)
#define OFF_BTOT  (OFF_BCAT + SZ_BCAT)
#define SZ_BTOT   256ull
#define OFF_LOG   (OFF_BTOT + SZ_BTOT)       // logits then ex (overwritten)
#define SZ_LOG    (2ull*400000ull)
#define OFF_MAX   (OFF_LOG + SZ_LOG)         // unsigned max-keys   (zeroed)
#define SZ_MAX    (2ull*25000ull)
#define OFF_DEN   (OFF_MAX + SZ_MAX)         // (zeroed)
#define SZ_DEN    (2ull*25000ull)
#define OFF_AGG   (OFF_DEN + SZ_DEN)         // (zeroed)
#define SZ_AGG    (25000ull*128ull)
#define OFF_CNT   (OFF_AGG + SZ_AGG)         // (zeroed)
#define SZ_CNT    25000ull
#define OFF_CUR   (OFF_CNT + SZ_CNT)
#define SZ_CUR    25000ull
#define OFF_PERM  (OFF_CUR + SZ_CUR)
#define SZ_PERM   400000ull

__device__ __forceinline__ unsigned fkey(float f) {
    unsigned u = __float_as_uint(f);
    return (u & 0x80000000u) ? ~u : (u | 0x80000000u);
}
__device__ __forceinline__ float keyf(unsigned k) {
    unsigned u = (k & 0x80000000u) ? (k & 0x7fffffffu) : ~k;
    return __uint_as_float(u);
}

// ---- K0: concat weights for node-pre GEMM; total bias ----
__global__ void k_prep(const float* __restrict__ niW, const float* __restrict__ njW,
                       const float* __restrict__ msgW,
                       const float* __restrict__ nib, const float* __restrict__ njb,
                       const float* __restrict__ eb,
                       float* __restrict__ bcat, float* __restrict__ btot) {
    int idx = blockIdx.x * 256 + threadIdx.x;
    if (idx < 128 * 640) {
        int k = idx / 640, c = idx % 640;
        float v = (c < 256) ? niW[k * 256 + c]
                : (c < 512) ? njW[k * 256 + (c - 256)]
                            : msgW[k * 128 + (c - 512)];
        bcat[idx] = v;
    }
    if (blockIdx.x == 0 && threadIdx.x < 256) {
        int c = threadIdx.x;
        btot[c] = nib[c] + njb[c] + eb[c];
    }
}

// shared inner GEMM tile: acc[4][8] += A[4 rows][64 k] * B[64 k][8 cols]
__device__ __forceinline__ void gemm_tile(const float* Al, int astride, int acol0,
                                          const float* Bl, int trow, int tcol,
                                          float acc[4][8]) {
    for (int k4 = 0; k4 < 64; k4 += 4) {
        float ar[4][4];
#pragma unroll
        for (int r = 0; r < 4; ++r)
            *(float4*)ar[r] = *(const float4*)&Al[(trow * 4 + r) * astride + acol0 + k4];
#pragma unroll
        for (int kk = 0; kk < 4; ++kk) {
            float4 b0 = *(const float4*)&Bl[(k4 + kk) * 128 + tcol * 8];
            float4 b1 = *(const float4*)&Bl[(k4 + kk) * 128 + tcol * 8 + 4];
            float bv[8] = {b0.x, b0.y, b0.z, b0.w, b1.x, b1.y, b1.z, b1.w};
#pragma unroll
            for (int r = 0; r < 4; ++r) {
                float av = ar[r][kk];
#pragma unroll
                for (int j = 0; j < 8; ++j) acc[r][j] = fmaf(av, bv[j], acc[r][j]);
            }
        }
    }
}

// ---- K1: pre = node_features @ bcat   [25000,128]@[128,640] ----
__global__ __launch_bounds__(256) void k_node_pre(const float* __restrict__ nf,
                                                  const float* __restrict__ bcat,
                                                  float* __restrict__ pre) {
    __shared__ float Al[64 * 128];
    __shared__ float Bl[64 * 128];
    int t = threadIdx.x, n0 = blockIdx.x * 64;
    int trow = t >> 4, tcol = t & 15;
#pragma unroll
    for (int q = 0; q < 8; ++q) {
        int g = t + 256 * q;
        int i = g >> 5, k4 = (g & 31) * 4;
        int n = n0 + i;
        float4 v = make_float4(0.f, 0.f, 0.f, 0.f);
        if (n < 25000) v = *(const float4*)&nf[(size_t)n * 128 + k4];
        *(float4*)&Al[i * 128 + k4] = v;
    }
    for (int cc = 0; cc < 5; ++cc) {
        float acc[4][8] = {};
        for (int kh = 0; kh < 2; ++kh) {
            __syncthreads();
#pragma unroll
            for (int q = 0; q < 8; ++q) {
                int g = t + 256 * q;
                int k = g >> 5, c4 = (g & 31) * 4;
                *(float4*)&Bl[k * 128 + c4] =
                    *(const float4*)&bcat[(kh * 64 + k) * 640 + cc * 128 + c4];
            }
            __syncthreads();
            gemm_tile(Al, 128, kh * 64, Bl, trow, tcol, acc);
        }
#pragma unroll
        for (int r = 0; r < 4; ++r) {
            int n = n0 + trow * 4 + r;
            if (n < 25000) {
                *(float4*)&pre[(size_t)n * 640 + cc * 128 + tcol * 8] =
                    make_float4(acc[r][0], acc[r][1], acc[r][2], acc[r][3]);
                *(float4*)&pre[(size_t)n * 640 + cc * 128 + tcol * 8 + 4] =
                    make_float4(acc[r][4], acc[r][5], acc[r][6], acc[r][7]);
            }
        }
        __syncthreads();
    }
}

// ---- K2a: histogram of dst ----
__global__ void k_hist(const int* __restrict__ eidx, int* __restrict__ count) {
    int e = blockIdx.x * 256 + threadIdx.x;
    if (e < 400000) atomicAdd(&count[eidx[e]], 1);
}

// ---- K2b: exclusive scan (single block) count -> cursor ----
__global__ __launch_bounds__(1024) void k_scan(const int* __restrict__ count,
                                               int* __restrict__ cursor) {
    __shared__ int sums[1024];
    int t = threadIdx.x;
    int base = t * 25;
    int v[25];
    int local = 0;
#pragma unroll
    for (int i = 0; i < 25; ++i) {
        int idx = base + i;
        int c = (idx < 25000) ? count[idx] : 0;
        v[i] = local;
        local += c;
    }
    sums[t] = local;
    __syncthreads();
    for (int off = 1; off < 1024; off <<= 1) {
        int x = (t >= off) ? sums[t - off] : 0;
        __syncthreads();
        sums[t] += x;
        __syncthreads();
    }
    int prefix = (t == 0) ? 0 : sums[t - 1];
#pragma unroll
    for (int i = 0; i < 25; ++i) {
        int idx = base + i;
        if (idx < 25000) cursor[idx] = prefix + v[i];
    }
}

// ---- K2c: scatter edge ids into dst-sorted order ----
__global__ void k_scatter(const int* __restrict__ eidx, int* __restrict__ cursor,
                          int* __restrict__ perm) {
    int e = blockIdx.x * 256 + threadIdx.x;
    if (e < 400000) {
        int d = eidx[e];
        int p = atomicAdd(&cursor[d], 1);
        perm[p] = e;
    }
}

// ---- K3: edge logits + atomic max ----
__global__ __launch_bounds__(256) void k_edge_logits(
        const float* __restrict__ ef, const int* __restrict__ eidx,
        const float* __restrict__ eW, const float* __restrict__ pre,
        const float* __restrict__ btot, const float* __restrict__ aproj,
        float* __restrict__ logits, unsigned* __restrict__ maxkey) {
    __shared__ float Al[64 * 68];
    __shared__ float Bl[64 * 128];
    __shared__ int dstl[64], srcl[64];
    int t = threadIdx.x, e0 = blockIdx.x * 64;
    int trow = t >> 4, tcol = t & 15;
#pragma unroll
    for (int q = 0; q < 4; ++q) {
        int g = t + 256 * q;
        int e = g >> 4, k4 = (g & 15) * 4;
        *(float4*)&Al[e * 68 + k4] = *(const float4*)&ef[(size_t)(e0 + e) * 64 + k4];
    }
    if (t < 64) { dstl[t] = eidx[e0 + t]; srcl[t] = eidx[400000 + e0 + t]; }
    for (int h = 0; h < 2; ++h) {
        __syncthreads();
#pragma unroll
        for (int q = 0; q < 8; ++q) {
            int g = t + 256 * q;
            int k = g >> 5, c4 = (g & 31) * 4;
            *(float4*)&Bl[k * 128 + c4] = *(const float4*)&eW[k * 256 + h * 128 + c4];
        }
        __syncthreads();
        float acc[4][8] = {};
        gemm_tile(Al, 68, 0, Bl, trow, tcol, acc);

        float bt[8], ap[8];
        *(float4*)bt = *(const float4*)&btot[h * 128 + tcol * 8];
        *(float4*)(bt + 4) = *(const float4*)&btot[h * 128 + tcol * 8 + 4];
        *(float4*)ap = *(const float4*)&aproj[h * 128 + tcol * 8];
        *(float4*)(ap + 4) = *(const float4*)&aproj[h * 128 + tcol * 8 + 4];
#pragma unroll
        for (int r = 0; r < 4; ++r) {
            int e = trow * 4 + r;
            int ed = dstl[e], es = srcl[e];
            float pi[8], pj[8];
            *(float4*)pi = *(const float4*)&pre[(size_t)ed * 640 + h * 128 + tcol * 8];
            *(float4*)(pi + 4) = *(const float4*)&pre[(size_t)ed * 640 + h * 128 + tcol * 8 + 4];
            *(float4*)pj = *(const float4*)&pre[(size_t)es * 640 + 256 + h * 128 + tcol * 8];
            *(float4*)(pj + 4) = *(const float4*)&pre[(size_t)es * 640 + 256 + h * 128 + tcol * 8 + 4];
            float p = 0.f;
#pragma unroll
            for (int j = 0; j < 8; ++j) {
                float hid = acc[r][j] + pi[j] + pj[j] + bt[j];
                hid = hid >= 0.f ? hid : NEG * hid;
                p = fmaf(hid, ap[j], p);
            }
            p += __shfl_xor(p, 1);
            p += __shfl_xor(p, 2);
            p += __shfl_xor(p, 4);
            p += __shfl_xor(p, 8);
            if (tcol == 0) {
                logits[(size_t)(e0 + e) * 2 + h] = p;
                atomicMax(&maxkey[ed * 2 + h], fkey(p));
            }
        }
    }
}

// ---- K4: ex = exp(logit - max); denom += ex ----
__global__ void k_soft(const int* __restrict__ eidx, float* __restrict__ logits,
                       const unsigned* __restrict__ maxkey, float* __restrict__ denom) {
    int idx = blockIdx.x * 256 + threadIdx.x;
    if (idx >= 800000) return;
    int e = idx >> 1, h = idx & 1;
    int ed = eidx[e];
    float m = keyf(maxkey[ed * 2 + h]);
    float ex = __expf(logits[idx] - m);
    logits[idx] = ex;
    atomicAdd(&denom[ed * 2 + h], ex);
}

// ---- K5: messages over dst-sorted edges + segmented-reduce scatter ----
__global__ __launch_bounds__(256) void k_messages(
        const float* __restrict__ ef, const int* __restrict__ eidx,
        const int* __restrict__ perm,
        const float* __restrict__ msgWb, const float* __restrict__ pre,
        const float* __restrict__ exbuf, const float* __restrict__ denom,
        float* __restrict__ agg) {
    __shared__ float S[64 * 68 + 64 * 128];  // Al | Bl ; Msg tile aliases S after GEMM
    __shared__ int dstl[64], srcl[64], eperm[64];
    __shared__ float attl[64 * 2];
    float* Al = S;
    float* Bl = S + 64 * 68;
    int t = threadIdx.x, p0 = blockIdx.x * 64;
    int trow = t >> 4, tcol = t & 15;

    if (t < 64) {
        int e = perm[p0 + t];
        eperm[t] = e;
        int d = eidx[e];
        dstl[t] = d;
        srcl[t] = eidx[400000 + e];
        attl[t * 2 + 0] = exbuf[(size_t)e * 2 + 0] / denom[d * 2 + 0];
        attl[t * 2 + 1] = exbuf[(size_t)e * 2 + 1] / denom[d * 2 + 1];
    }
#pragma unroll
    for (int q = 0; q < 8; ++q) {
        int g = t + 256 * q;
        int k = g >> 5, c4 = (g & 31) * 4;
        *(float4*)&Bl[k * 128 + c4] = *(const float4*)&msgWb[k * 128 + c4];
    }
    __syncthreads();  // eperm ready
#pragma unroll
    for (int q = 0; q < 4; ++q) {
        int g = t + 256 * q;
        int i = g >> 4, k4 = (g & 15) * 4;
        int e = eperm[i];
        *(float4*)&Al[i * 68 + k4] = *(const float4*)&ef[(size_t)e * 64 + k4];
    }
    __syncthreads();
    float acc[4][8] = {};
    gemm_tile(Al, 68, 0, Bl, trow, tcol, acc);

    // weighted message (regs only, no LDS access)
    int h = tcol >> 3;
    float wmsg[4][8];
#pragma unroll
    for (int r = 0; r < 4; ++r) {
        int i = trow * 4 + r;
        int es = srcl[i];
        float pm[8];
        *(float4*)pm = *(const float4*)&pre[(size_t)es * 640 + 512 + tcol * 8];
        *(float4*)(pm + 4) = *(const float4*)&pre[(size_t)es * 640 + 512 + tcol * 8 + 4];
        float a = attl[i * 2 + h];
#pragma unroll
        for (int j = 0; j < 8; ++j) wmsg[r][j] = a * (acc[r][j] + pm[j]);
    }
    __syncthreads();  // all GEMM LDS reads done; safe to overwrite S
    float* Msg = S;   // [64][128]
#pragma unroll
    for (int r = 0; r < 4; ++r) {
        int i = trow * 4 + r;
        *(float4*)&Msg[i * 128 + tcol * 8]     = *(float4*)&wmsg[r][0];
        *(float4*)&Msg[i * 128 + tcol * 8 + 4] = *(float4*)&wmsg[r][4];
    }
    __syncthreads();

    // segmented reduction over sorted dst; one atomic per (run, col)
    int c = t & 127, half = t >> 7;
    int r0 = half * 32, r1 = r0 + 32;
    int cur = dstl[r0];
    float sum = 0.f;
    for (int r = r0; r < r1; ++r) {
        int d = dstl[r];
        if (d != cur) {
            atomicAdd(&agg[(size_t)cur * 128 + c], sum);
            sum = 0.f;
            cur = d;
        }
        sum += Msg[r * 128 + c];
    }
    atomicAdd(&agg[(size_t)cur * 128 + c], sum);
}

// ---- K6: out = (agg + msg_b*[has_edges]) @ out_W + out_b ----
__global__ __launch_bounds__(256) void k_out(
        const float* __restrict__ agg, const float* __restrict__ denom,
        const float* __restrict__ msgb, const float* __restrict__ outW,
        const float* __restrict__ outb, float* __restrict__ out) {
    __shared__ float Al[64 * 128];
    __shared__ float Bl[64 * 128];
    int t = threadIdx.x, n0 = blockIdx.x * 64;
    int trow = t >> 4, tcol = t & 15;
#pragma unroll
    for (int q = 0; q < 8; ++q) {
        int g = t + 256 * q;
        int i = g >> 5, k4 = (g & 31) * 4;
        int n = n0 + i;
        float4 v = make_float4(0.f, 0.f, 0.f, 0.f);
        if (n < 25000) {
            v = *(const float4*)&agg[(size_t)n * 128 + k4];
            if (denom[n * 2 + (k4 >> 6)] > 0.f) {
                float4 mb = *(const float4*)&msgb[k4];
                v.x += mb.x; v.y += mb.y; v.z += mb.z; v.w += mb.w;
            }
        }
        *(float4*)&Al[i * 128 + k4] = v;
    }
    float acc[4][8] = {};
    for (int kh = 0; kh < 2; ++kh) {
        __syncthreads();
#pragma unroll
        for (int q = 0; q < 8; ++q) {
            int g = t + 256 * q;
            int k = g >> 5, c4 = (g & 31) * 4;
            *(float4*)&Bl[k * 128 + c4] = *(const float4*)&outW[(kh * 64 + k) * 128 + c4];
        }
        __syncthreads();
        gemm_tile(Al, 128, kh * 64, Bl, trow, tcol, acc);
    }
    float ob[8];
    *(float4*)ob = *(const float4*)&outb[tcol * 8];
    *(float4*)(ob + 4) = *(const float4*)&outb[tcol * 8 + 4];
#pragma unroll
    for (int r = 0; r < 4; ++r) {
        int n = n0 + trow * 4 + r;
        if (n < 25000) {
            *(float4*)&out[(size_t)n * 128 + tcol * 8] =
                make_float4(acc[r][0] + ob[0], acc[r][1] + ob[1], acc[r][2] + ob[2], acc[r][3] + ob[3]);
            *(float4*)&out[(size_t)n * 128 + tcol * 8 + 4] =
                make_float4(acc[r][4] + ob[4], acc[r][5] + ob[5], acc[r][6] + ob[6], acc[r][7] + ob[7]);
        }
    }
}

extern "C" void kernel_launch(void* const* d_in, const int* in_sizes, int n_in,
                              void* d_out, int out_size, void* d_ws, size_t ws_size,
                              hipStream_t stream) {
    const float* nf    = (const float*)d_in[0];
    const float* ef    = (const float*)d_in[1];
    const int*   eidx  = (const int*)d_in[2];
    const float* niW   = (const float*)d_in[3];
    const float* nib   = (const float*)d_in[4];
    const float* njW   = (const float*)d_in[5];
    const float* njb   = (const float*)d_in[6];
    const float* eW    = (const float*)d_in[7];
    const float* eb    = (const float*)d_in[8];
    const float* aproj = (const float*)d_in[9];
    const float* msgW  = (const float*)d_in[10];
    const float* msgb  = (const float*)d_in[11];
    const float* outW  = (const float*)d_in[12];
    const float* outb  = (const float*)d_in[13];

    float* ws = (float*)d_ws;
    float* pre       = ws + OFF_PRE;
    float* bcat      = ws + OFF_BCAT;
    float* btot      = ws + OFF_BTOT;
    float* logits    = ws + OFF_LOG;
    unsigned* maxkey = (unsigned*)(ws + OFF_MAX);
    float* denom     = ws + OFF_DEN;
    float* agg       = ws + OFF_AGG;
    int*   count     = (int*)(ws + OFF_CNT);
    int*   cursor    = (int*)(ws + OFF_CUR);
    int*   perm      = (int*)(ws + OFF_PERM);

    // zero maxkey + denom + agg + count (contiguous)
    hipMemsetAsync(ws + OFF_MAX, 0, (size_t)(SZ_MAX + SZ_DEN + SZ_AGG + SZ_CNT) * 4, stream);

    k_prep<<<320, 256, 0, stream>>>(niW, njW, msgW, nib, njb, eb, bcat, btot);
    k_node_pre<<<391, 256, 0, stream>>>(nf, bcat, pre);
    k_hist<<<1563, 256, 0, stream>>>(eidx, count);
    k_scan<<<1, 1024, 0, stream>>>(count, cursor);
    k_scatter<<<1563, 256, 0, stream>>>(eidx, cursor, perm);
    k_edge_logits<<<6250, 256, 0, stream>>>(ef, eidx, eW, pre, btot, aproj, logits, maxkey);
    k_soft<<<3125, 256, 0, stream>>>(eidx, logits, maxkey, denom);
    k_messages<<<6250, 256, 0, stream>>>(ef, eidx, perm, msgW + 128 * 128, pre, logits, denom, agg);
    k_out<<<391, 256, 0, stream>>>(agg, denom, msgb, outW, outb, (float*)d_out);
}

// Round 3
// 389.001 us; speedup vs baseline: 4.4325x; 1.2876x over previous
//
#include <hip/hip_runtime.h>

#define NEG 0.2f
typedef unsigned short u16;
typedef __bf16 bf8 __attribute__((ext_vector_type(8)));
typedef float f4 __attribute__((ext_vector_type(4)));

// ---- workspace layout (in floats) ----
#define OFF_PRE   0ull
#define SZ_PRE    (25000ull*640ull)          // pre: [n][0:256)=ni, [256:512)=nj, [512:640)=msg part
#define OFF_BCAT  (OFF_PRE + SZ_PRE)
#define SZ_BCAT   (128ull*640ull)
#define OFF_BTOT  (OFF_BCAT + SZ_BCAT)
#define SZ_BTOT   256ull
#define OFF_LOG   (OFF_BTOT + SZ_BTOT)       // logits then ex (overwritten)
#define SZ_LOG    (2ull*400000ull)
#define OFF_MAX   (OFF_LOG + SZ_LOG)         // unsigned max-keys   (zeroed)
#define SZ_MAX    (2ull*25000ull)
#define OFF_DEN   (OFF_MAX + SZ_MAX)         // (zeroed)
#define SZ_DEN    (2ull*25000ull)
#define OFF_AGG   (OFF_DEN + SZ_DEN)         // (zeroed)
#define SZ_AGG    (25000ull*128ull)
#define OFF_CNT   (OFF_AGG + SZ_AGG)         // (zeroed)
#define SZ_CNT    25000ull
#define OFF_CUR   (OFF_CNT + SZ_CNT)
#define SZ_CUR    25000ull
#define OFF_PERM  (OFF_CUR + SZ_CUR)
#define SZ_PERM   400000ull
#define OFF_EWF   (OFF_PERM + SZ_PERM)       // ushort[16384] MFMA-frag-packed e_W (bf16)
#define SZ_EWF    8192ull
#define OFF_MWF   (OFF_EWF + SZ_EWF)         // ushort[8192] MFMA-frag-packed msg_W edge half
#define SZ_MWF    4096ull

__device__ __forceinline__ unsigned fkey(float f) {
    unsigned u = __float_as_uint(f);
    return (u & 0x80000000u) ? ~u : (u | 0x80000000u);
}
__device__ __forceinline__ float keyf(unsigned k) {
    unsigned u = (k & 0x80000000u) ? (k & 0x7fffffffu) : ~k;
    return __uint_as_float(u);
}
// f32 -> bf16 bits, round-to-nearest-even
__device__ __forceinline__ u16 f2b(float f) {
    unsigned u = __float_as_uint(f);
    return (u16)((u + 0x7FFFu + ((u >> 16) & 1u)) >> 16);
}
__device__ __forceinline__ bf8 pack8(float4 a, float4 b) {
    union { u16 u[8]; bf8 v; } x;
    x.u[0] = f2b(a.x); x.u[1] = f2b(a.y); x.u[2] = f2b(a.z); x.u[3] = f2b(a.w);
    x.u[4] = f2b(b.x); x.u[5] = f2b(b.y); x.u[6] = f2b(b.z); x.u[7] = f2b(b.w);
    return x.v;
}

// ---- K0: concat weights for node-pre GEMM; total bias; MFMA frag packing ----
__global__ void k_prep(const float* __restrict__ niW, const float* __restrict__ njW,
                       const float* __restrict__ msgW, const float* __restrict__ eW,
                       const float* __restrict__ nib, const float* __restrict__ njb,
                       const float* __restrict__ eb,
                       float* __restrict__ bcat, float* __restrict__ btot,
                       u16* __restrict__ ewfrag, u16* __restrict__ msgfrag) {
    int idx = blockIdx.x * 256 + threadIdx.x;
    if (idx < 128 * 640) {
        int k = idx / 640, c = idx % 640;
        float v = (c < 256) ? niW[k * 256 + c]
                : (c < 512) ? njW[k * 256 + (c - 256)]
                            : msgW[k * 128 + (c - 512)];
        bcat[idx] = v;
    }
    // ewfrag[((c*2+s)*64+lane)*8+i] = bf16(eW[k][col]), k=s*32+(lane>>4)*8+i, col=c*16+(lane&15)
    if (idx < 16384) {
        int c = idx >> 10, s = (idx >> 9) & 1, ln = (idx >> 3) & 63, i = idx & 7;
        int k = s * 32 + ((ln >> 4) << 3) + i;
        int col = c * 16 + (ln & 15);
        ewfrag[idx] = f2b(eW[k * 256 + col]);
    }
    if (idx < 8192) {
        int c = idx >> 10, s = (idx >> 9) & 1, ln = (idx >> 3) & 63, i = idx & 7;
        int k = s * 32 + ((ln >> 4) << 3) + i;
        int col = c * 16 + (ln & 15);
        msgfrag[idx] = f2b(msgW[(128 + k) * 128 + col]);
    }
    if (blockIdx.x == 0 && threadIdx.x < 256) {
        int c = threadIdx.x;
        btot[c] = nib[c] + njb[c] + eb[c];
    }
}

// shared inner GEMM tile (f32 VALU): acc[4][8] += A[4r][64k] * B[64k][8c]
__device__ __forceinline__ void gemm_tile(const float* Al, int astride, int acol0,
                                          const float* Bl, int trow, int tcol,
                                          float acc[4][8]) {
    for (int k4 = 0; k4 < 64; k4 += 4) {
        float ar[4][4];
#pragma unroll
        for (int r = 0; r < 4; ++r)
            *(float4*)ar[r] = *(const float4*)&Al[(trow * 4 + r) * astride + acol0 + k4];
#pragma unroll
        for (int kk = 0; kk < 4; ++kk) {
            float4 b0 = *(const float4*)&Bl[(k4 + kk) * 128 + tcol * 8];
            float4 b1 = *(const float4*)&Bl[(k4 + kk) * 128 + tcol * 8 + 4];
            float bv[8] = {b0.x, b0.y, b0.z, b0.w, b1.x, b1.y, b1.z, b1.w};
#pragma unroll
            for (int r = 0; r < 4; ++r) {
                float av = ar[r][kk];
#pragma unroll
                for (int j = 0; j < 8; ++j) acc[r][j] = fmaf(av, bv[j], acc[r][j]);
            }
        }
    }
}

// ---- K1: pre = node_features @ bcat   [25000,128]@[128,640] ----
__global__ __launch_bounds__(256) void k_node_pre(const float* __restrict__ nf,
                                                  const float* __restrict__ bcat,
                                                  float* __restrict__ pre) {
    __shared__ float Al[64 * 128];
    __shared__ float Bl[64 * 128];
    int t = threadIdx.x, n0 = blockIdx.x * 64;
    int trow = t >> 4, tcol = t & 15;
#pragma unroll
    for (int q = 0; q < 8; ++q) {
        int g = t + 256 * q;
        int i = g >> 5, k4 = (g & 31) * 4;
        int n = n0 + i;
        float4 v = make_float4(0.f, 0.f, 0.f, 0.f);
        if (n < 25000) v = *(const float4*)&nf[(size_t)n * 128 + k4];
        *(float4*)&Al[i * 128 + k4] = v;
    }
    for (int cc = 0; cc < 5; ++cc) {
        float acc[4][8] = {};
        for (int kh = 0; kh < 2; ++kh) {
            __syncthreads();
#pragma unroll
            for (int q = 0; q < 8; ++q) {
                int g = t + 256 * q;
                int k = g >> 5, c4 = (g & 31) * 4;
                *(float4*)&Bl[k * 128 + c4] =
                    *(const float4*)&bcat[(kh * 64 + k) * 640 + cc * 128 + c4];
            }
            __syncthreads();
            gemm_tile(Al, 128, kh * 64, Bl, trow, tcol, acc);
        }
#pragma unroll
        for (int r = 0; r < 4; ++r) {
            int n = n0 + trow * 4 + r;
            if (n < 25000) {
                *(float4*)&pre[(size_t)n * 640 + cc * 128 + tcol * 8] =
                    make_float4(acc[r][0], acc[r][1], acc[r][2], acc[r][3]);
                *(float4*)&pre[(size_t)n * 640 + cc * 128 + tcol * 8 + 4] =
                    make_float4(acc[r][4], acc[r][5], acc[r][6], acc[r][7]);
            }
        }
        __syncthreads();
    }
}

// ---- K2a: histogram of dst ----
__global__ void k_hist(const int* __restrict__ eidx, int* __restrict__ count) {
    int e = blockIdx.x * 256 + threadIdx.x;
    if (e < 400000) atomicAdd(&count[eidx[e]], 1);
}

// ---- K2b: exclusive scan (single block) count -> cursor ----
__global__ __launch_bounds__(1024) void k_scan(const int* __restrict__ count,
                                               int* __restrict__ cursor) {
    __shared__ int sums[1024];
    int t = threadIdx.x;
    int base = t * 25;
    int v[25];
    int local = 0;
#pragma unroll
    for (int i = 0; i < 25; ++i) {
        int idx = base + i;
        int c = (idx < 25000) ? count[idx] : 0;
        v[i] = local;
        local += c;
    }
    sums[t] = local;
    __syncthreads();
    for (int off = 1; off < 1024; off <<= 1) {
        int x = (t >= off) ? sums[t - off] : 0;
        __syncthreads();
        sums[t] += x;
        __syncthreads();
    }
    int prefix = (t == 0) ? 0 : sums[t - 1];
#pragma unroll
    for (int i = 0; i < 25; ++i) {
        int idx = base + i;
        if (idx < 25000) cursor[idx] = prefix + v[i];
    }
}

// ---- K2c: scatter edge ids into dst-sorted order ----
__global__ void k_scatter(const int* __restrict__ eidx, int* __restrict__ cursor,
                          int* __restrict__ perm) {
    int e = blockIdx.x * 256 + threadIdx.x;
    if (e < 400000) {
        int d = eidx[e];
        int p = atomicAdd(&cursor[d], 1);
        perm[p] = e;
    }
}

// ---- K3: edge logits via bf16 MFMA + atomic max (no LDS) ----
__global__ __launch_bounds__(256) void k_edge_logits(
        const float* __restrict__ ef, const int* __restrict__ eidx,
        const u16* __restrict__ ewfrag, const float* __restrict__ pre,
        const float* __restrict__ btot, const float* __restrict__ aproj,
        float* __restrict__ logits, unsigned* __restrict__ maxkey) {
    int t = threadIdx.x;
    int w = t >> 6, l = t & 63;
    int e0 = blockIdx.x * 64 + w * 16;      // this wave's 16 edges
    int row = l & 15, kb = l >> 4;

    // A frags: lane holds ef[e0+row][kb*8+i] (k 0..31) and +32 (k 32..63)
    const float* ap = &ef[(size_t)(e0 + row) * 64 + kb * 8];
    float4 a00 = *(const float4*)ap;
    float4 a01 = *(const float4*)(ap + 4);
    float4 a10 = *(const float4*)(ap + 32);
    float4 a11 = *(const float4*)(ap + 36);
    bf8 a0 = pack8(a00, a01), a1 = pack8(a10, a11);

    // epilogue rows: C row = kb*4 + r
    int ed[4], es[4];
#pragma unroll
    for (int r = 0; r < 4; ++r) {
        int e = e0 + kb * 4 + r;
        ed[r] = eidx[e];
        es[r] = eidx[400000 + e];
    }

    float part0[4] = {0.f, 0.f, 0.f, 0.f}, part1[4] = {0.f, 0.f, 0.f, 0.f};
#pragma unroll
    for (int c = 0; c < 16; ++c) {
        bf8 b0 = *(const bf8*)&ewfrag[(size_t)((c * 2 + 0) * 64 + l) * 8];
        bf8 b1 = *(const bf8*)&ewfrag[(size_t)((c * 2 + 1) * 64 + l) * 8];
        f4 acc = {0.f, 0.f, 0.f, 0.f};
        acc = __builtin_amdgcn_mfma_f32_16x16x32_bf16(a0, b0, acc, 0, 0, 0);
        acc = __builtin_amdgcn_mfma_f32_16x16x32_bf16(a1, b1, acc, 0, 0, 0);
        int col = c * 16 + row;             // C col = lane&15
        float bt = btot[col], apj = aproj[col];
#pragma unroll
        for (int r = 0; r < 4; ++r) {
            float hid = acc[r] + pre[(size_t)ed[r] * 640 + col]
                               + pre[(size_t)es[r] * 640 + 256 + col] + bt;
            hid = hid >= 0.f ? hid : NEG * hid;
            if (c < 8) part0[r] = fmaf(hid, apj, part0[r]);
            else       part1[r] = fmaf(hid, apj, part1[r]);
        }
    }
    // reduce over the 16 col-lanes (low 4 lane bits)
#pragma unroll
    for (int m = 1; m < 16; m <<= 1) {
#pragma unroll
        for (int r = 0; r < 4; ++r) {
            part0[r] += __shfl_xor(part0[r], m);
            part1[r] += __shfl_xor(part1[r], m);
        }
    }
    if (row == 0) {
#pragma unroll
        for (int r = 0; r < 4; ++r) {
            int e = e0 + kb * 4 + r;
            logits[(size_t)e * 2 + 0] = part0[r];
            logits[(size_t)e * 2 + 1] = part1[r];
            atomicMax(&maxkey[ed[r] * 2 + 0], fkey(part0[r]));
            atomicMax(&maxkey[ed[r] * 2 + 1], fkey(part1[r]));
        }
    }
}

// ---- K4: ex = exp(logit - max); denom += ex ----
__global__ void k_soft(const int* __restrict__ eidx, float* __restrict__ logits,
                       const unsigned* __restrict__ maxkey, float* __restrict__ denom) {
    int idx = blockIdx.x * 256 + threadIdx.x;
    if (idx >= 800000) return;
    int e = idx >> 1, h = idx & 1;
    int ed = eidx[e];
    float m = keyf(maxkey[ed * 2 + h]);
    float ex = __expf(logits[idx] - m);
    logits[idx] = ex;
    atomicAdd(&denom[ed * 2 + h], ex);
}

// ---- K5: messages via bf16 MFMA over dst-sorted edges + segmented reduce ----
__global__ __launch_bounds__(256) void k_messages(
        const float* __restrict__ ef, const int* __restrict__ eidx,
        const int* __restrict__ perm, const u16* __restrict__ msgfrag,
        const float* __restrict__ pre, const float* __restrict__ exbuf,
        const float* __restrict__ denom, float* __restrict__ agg) {
    __shared__ float Msg[64 * 132];
    __shared__ int dstl[64], srcl[64], eperm[64];
    __shared__ float attl[64][2];
    int t = threadIdx.x;
    int w = t >> 6, l = t & 63;
    int p0 = blockIdx.x * 64;
    int row = l & 15, kb = l >> 4;

    if (t < 64) {
        int e = perm[p0 + t];
        eperm[t] = e;
        int d = eidx[e];
        dstl[t] = d;
        srcl[t] = eidx[400000 + e];
        attl[t][0] = exbuf[(size_t)e * 2 + 0] / denom[d * 2 + 0];
        attl[t][1] = exbuf[(size_t)e * 2 + 1] / denom[d * 2 + 1];
    }
    __syncthreads();

    int ea = eperm[w * 16 + row];
    const float* apr = &ef[(size_t)ea * 64 + kb * 8];
    float4 a00 = *(const float4*)apr;
    float4 a01 = *(const float4*)(apr + 4);
    float4 a10 = *(const float4*)(apr + 32);
    float4 a11 = *(const float4*)(apr + 36);
    bf8 a0 = pack8(a00, a01), a1 = pack8(a10, a11);

    int esr[4];
    float at0[4], at1[4];
#pragma unroll
    for (int r = 0; r < 4; ++r) {
        int i4 = w * 16 + kb * 4 + r;
        esr[r] = srcl[i4];
        at0[r] = attl[i4][0];
        at1[r] = attl[i4][1];
    }

#pragma unroll
    for (int c = 0; c < 8; ++c) {
        bf8 b0 = *(const bf8*)&msgfrag[(size_t)((c * 2 + 0) * 64 + l) * 8];
        bf8 b1 = *(const bf8*)&msgfrag[(size_t)((c * 2 + 1) * 64 + l) * 8];
        f4 acc = {0.f, 0.f, 0.f, 0.f};
        acc = __builtin_amdgcn_mfma_f32_16x16x32_bf16(a0, b0, acc, 0, 0, 0);
        acc = __builtin_amdgcn_mfma_f32_16x16x32_bf16(a1, b1, acc, 0, 0, 0);
        int col = c * 16 + row;             // msg col 0..127; head = col>>6 = c>>2
#pragma unroll
        for (int r = 0; r < 4; ++r) {
            float m = acc[r] + pre[(size_t)esr[r] * 640 + 512 + col];
            float wm = ((c < 4) ? at0[r] : at1[r]) * m;
            Msg[(w * 16 + kb * 4 + r) * 132 + col] = wm;
        }
    }
    __syncthreads();

    // segmented reduction over sorted dst; one atomic per (run, col)
    int c = t & 127, half = t >> 7;
    int r0 = half * 32, r1 = r0 + 32;
    int cur = dstl[r0];
    float sum = 0.f;
    for (int r = r0; r < r1; ++r) {
        int d = dstl[r];
        if (d != cur) {
            atomicAdd(&agg[(size_t)cur * 128 + c], sum);
            sum = 0.f;
            cur = d;
        }
        sum += Msg[r * 132 + c];
    }
    atomicAdd(&agg[(size_t)cur * 128 + c], sum);
}

// ---- K6: out = (agg + msg_b*[has_edges]) @ out_W + out_b ----
__global__ __launch_bounds__(256) void k_out(
        const float* __restrict__ agg, const float* __restrict__ denom,
        const float* __restrict__ msgb, const float* __restrict__ outW,
        const float* __restrict__ outb, float* __restrict__ out) {
    __shared__ float Al[64 * 128];
    __shared__ float Bl[64 * 128];
    int t = threadIdx.x, n0 = blockIdx.x * 64;
    int trow = t >> 4, tcol = t & 15;
#pragma unroll
    for (int q = 0; q < 8; ++q) {
        int g = t + 256 * q;
        int i = g >> 5, k4 = (g & 31) * 4;
        int n = n0 + i;
        float4 v = make_float4(0.f, 0.f, 0.f, 0.f);
        if (n < 25000) {
            v = *(const float4*)&agg[(size_t)n * 128 + k4];
            if (denom[n * 2 + (k4 >> 6)] > 0.f) {
                float4 mb = *(const float4*)&msgb[k4];
                v.x += mb.x; v.y += mb.y; v.z += mb.z; v.w += mb.w;
            }
        }
        *(float4*)&Al[i * 128 + k4] = v;
    }
    float acc[4][8] = {};
    for (int kh = 0; kh < 2; ++kh) {
        __syncthreads();
#pragma unroll
        for (int q = 0; q < 8; ++q) {
            int g = t + 256 * q;
            int k = g >> 5, c4 = (g & 31) * 4;
            *(float4*)&Bl[k * 128 + c4] = *(const float4*)&outW[(kh * 64 + k) * 128 + c4];
        }
        __syncthreads();
        gemm_tile(Al, 128, kh * 64, Bl, trow, tcol, acc);
    }
    float ob[8];
    *(float4*)ob = *(const float4*)&outb[tcol * 8];
    *(float4*)(ob + 4) = *(const float4*)&outb[tcol * 8 + 4];
#pragma unroll
    for (int r = 0; r < 4; ++r) {
        int n = n0 + trow * 4 + r;
        if (n < 25000) {
            *(float4*)&out[(size_t)n * 128 + tcol * 8] =
                make_float4(acc[r][0] + ob[0], acc[r][1] + ob[1], acc[r][2] + ob[2], acc[r][3] + ob[3]);
            *(float4*)&out[(size_t)n * 128 + tcol * 8 + 4] =
                make_float4(acc[r][4] + ob[4], acc[r][5] + ob[5], acc[r][6] + ob[6], acc[r][7] + ob[7]);
        }
    }
}

extern "C" void kernel_launch(void* const* d_in, const int* in_sizes, int n_in,
                              void* d_out, int out_size, void* d_ws, size_t ws_size,
                              hipStream_t stream) {
    const float* nf    = (const float*)d_in[0];
    const float* ef    = (const float*)d_in[1];
    const int*   eidx  = (const int*)d_in[2];
    const float* niW   = (const float*)d_in[3];
    const float* nib   = (const float*)d_in[4];
    const float* njW   = (const float*)d_in[5];
    const float* njb   = (const float*)d_in[6];
    const float* eW    = (const float*)d_in[7];
    const float* eb    = (const float*)d_in[8];
    const float* aproj = (const float*)d_in[9];
    const float* msgW  = (const float*)d_in[10];
    const float* msgb  = (const float*)d_in[11];
    const float* outW  = (const float*)d_in[12];
    const float* outb  = (const float*)d_in[13];

    float* ws = (float*)d_ws;
    float* pre       = ws + OFF_PRE;
    float* bcat      = ws + OFF_BCAT;
    float* btot      = ws + OFF_BTOT;
    float* logits    = ws + OFF_LOG;
    unsigned* maxkey = (unsigned*)(ws + OFF_MAX);
    float* denom     = ws + OFF_DEN;
    float* agg       = ws + OFF_AGG;
    int*   count     = (int*)(ws + OFF_CNT);
    int*   cursor    = (int*)(ws + OFF_CUR);
    int*   perm      = (int*)(ws + OFF_PERM);
    u16*   ewfrag    = (u16*)(ws + OFF_EWF);
    u16*   msgfrag   = (u16*)(ws + OFF_MWF);

    // zero maxkey + denom + agg + count (contiguous)
    hipMemsetAsync(ws + OFF_MAX, 0, (size_t)(SZ_MAX + SZ_DEN + SZ_AGG + SZ_CNT) * 4, stream);

    k_prep<<<320, 256, 0, stream>>>(niW, njW, msgW, eW, nib, njb, eb, bcat, btot, ewfrag, msgfrag);
    k_node_pre<<<391, 256, 0, stream>>>(nf, bcat, pre);
    k_hist<<<1563, 256, 0, stream>>>(eidx, count);
    k_scan<<<1, 1024, 0, stream>>>(count, cursor);
    k_scatter<<<1563, 256, 0, stream>>>(eidx, cursor, perm);
    k_edge_logits<<<6250, 256, 0, stream>>>(ef, eidx, ewfrag, pre, btot, aproj, logits, maxkey);
    k_soft<<<3125, 256, 0, stream>>>(eidx, logits, maxkey, denom);
    k_messages<<<6250, 256, 0, stream>>>(ef, eidx, perm, msgfrag, pre, logits, denom, agg);
    k_out<<<391, 256, 0, stream>>>(agg, denom, msgb, outW, outb, (float*)d_out);
}

// Round 4
// 364.351 us; speedup vs baseline: 4.7324x; 1.0677x over previous
//
#include <hip/hip_runtime.h>

#define NEG 0.2f
typedef unsigned short u16;
typedef __bf16 bf8 __attribute__((ext_vector_type(8)));
typedef float f4 __attribute__((ext_vector_type(4)));
typedef u16 u16x8 __attribute__((ext_vector_type(8)));

// ---- workspace layout (in floats) ----
#define OFF_PREM  0ull                        // f32 [25000][128] msg-part of pre
#define SZ_PREM   (25000ull*128ull)
#define OFF_P16   (OFF_PREM + SZ_PREM)        // u16 [25000][512]: [0:256)=ni, [256:512)=nj (bf16)
#define SZ_P16    (25000ull*256ull)           // in floats (512 u16 = 256 f32)
#define OFF_BCAT  (OFF_P16 + SZ_P16)
#define SZ_BCAT   (128ull*640ull)
#define OFF_BTOT  (OFF_BCAT + SZ_BCAT)
#define SZ_BTOT   256ull
#define OFF_LOG   (OFF_BTOT + SZ_BTOT)        // logits then ex, SORTED space [p][2]
#define SZ_LOG    (2ull*400000ull)
#define OFF_MAX   (OFF_LOG + SZ_LOG)          // unsigned max-keys   (zeroed)
#define SZ_MAX    (2ull*25000ull)
#define OFF_DEN   (OFF_MAX + SZ_MAX)          // (zeroed)
#define SZ_DEN    (2ull*25000ull)
#define OFF_AGG   (OFF_DEN + SZ_DEN)          // (zeroed)
#define SZ_AGG    (25000ull*128ull)
#define OFF_CNT   (OFF_AGG + SZ_AGG)          // (zeroed)
#define SZ_CNT    25000ull
#define OFF_CUR   (OFF_CNT + SZ_CNT)
#define SZ_CUR    25000ull
#define OFF_PERM  (OFF_CUR + SZ_CUR)
#define SZ_PERM   400000ull
#define OFF_DST   (OFF_PERM + SZ_PERM)        // dst per sorted pos
#define SZ_DST    400000ull
#define OFF_SRC   (OFF_DST + SZ_DST)          // src per sorted pos
#define SZ_SRC    400000ull
#define OFF_EWF   (OFF_SRC + SZ_SRC)          // u16[16384] MFMA-frag-packed e_W
#define SZ_EWF    8192ull
#define OFF_MWF   (OFF_EWF + SZ_EWF)          // u16[8192] MFMA-frag-packed msg_W edge half
#define SZ_MWF    4096ull

__device__ __forceinline__ unsigned fkey(float f) {
    unsigned u = __float_as_uint(f);
    return (u & 0x80000000u) ? ~u : (u | 0x80000000u);
}
__device__ __forceinline__ float keyf(unsigned k) {
    unsigned u = (k & 0x80000000u) ? (k & 0x7fffffffu) : ~k;
    return __uint_as_float(u);
}
// f32 -> bf16 bits, round-to-nearest-even
__device__ __forceinline__ u16 f2b(float f) {
    unsigned u = __float_as_uint(f);
    return (u16)((u + 0x7FFFu + ((u >> 16) & 1u)) >> 16);
}
__device__ __forceinline__ float b2f(u16 v) {
    return __uint_as_float(((unsigned)v) << 16);
}
__device__ __forceinline__ bf8 pack8(float4 a, float4 b) {
    union { u16 u[8]; bf8 v; } x;
    x.u[0] = f2b(a.x); x.u[1] = f2b(a.y); x.u[2] = f2b(a.z); x.u[3] = f2b(a.w);
    x.u[4] = f2b(b.x); x.u[5] = f2b(b.y); x.u[6] = f2b(b.z); x.u[7] = f2b(b.w);
    return x.v;
}

// ---- K0: concat weights; total bias; MFMA frag packing ----
__global__ void k_prep(const float* __restrict__ niW, const float* __restrict__ njW,
                       const float* __restrict__ msgW, const float* __restrict__ eW,
                       const float* __restrict__ nib, const float* __restrict__ njb,
                       const float* __restrict__ eb,
                       float* __restrict__ bcat, float* __restrict__ btot,
                       u16* __restrict__ ewfrag, u16* __restrict__ msgfrag) {
    int idx = blockIdx.x * 256 + threadIdx.x;
    if (idx < 128 * 640) {
        int k = idx / 640, c = idx % 640;
        float v = (c < 256) ? niW[k * 256 + c]
                : (c < 512) ? njW[k * 256 + (c - 256)]
                            : msgW[k * 128 + (c - 512)];
        bcat[idx] = v;
    }
    // ewfrag[((c*2+s)*64+lane)*8+i] = bf16(eW[k][col]), k=s*32+(lane>>4)*8+i, col=c*16+(lane&15)
    if (idx < 16384) {
        int c = idx >> 10, s = (idx >> 9) & 1, ln = (idx >> 3) & 63, i = idx & 7;
        int k = s * 32 + ((ln >> 4) << 3) + i;
        int col = c * 16 + (ln & 15);
        ewfrag[idx] = f2b(eW[k * 256 + col]);
    }
    if (idx < 8192) {
        int c = idx >> 10, s = (idx >> 9) & 1, ln = (idx >> 3) & 63, i = idx & 7;
        int k = s * 32 + ((ln >> 4) << 3) + i;
        int col = c * 16 + (ln & 15);
        msgfrag[idx] = f2b(msgW[(128 + k) * 128 + col]);
    }
    if (blockIdx.x == 0 && threadIdx.x < 256) {
        int c = threadIdx.x;
        btot[c] = nib[c] + njb[c] + eb[c];
    }
}

// shared inner GEMM tile (f32 VALU): acc[4][8] += A[4r][64k] * B[64k][8c]
__device__ __forceinline__ void gemm_tile(const float* Al, int astride, int acol0,
                                          const float* Bl, int trow, int tcol,
                                          float acc[4][8]) {
    for (int k4 = 0; k4 < 64; k4 += 4) {
        float ar[4][4];
#pragma unroll
        for (int r = 0; r < 4; ++r)
            *(float4*)ar[r] = *(const float4*)&Al[(trow * 4 + r) * astride + acol0 + k4];
#pragma unroll
        for (int kk = 0; kk < 4; ++kk) {
            float4 b0 = *(const float4*)&Bl[(k4 + kk) * 128 + tcol * 8];
            float4 b1 = *(const float4*)&Bl[(k4 + kk) * 128 + tcol * 8 + 4];
            float bv[8] = {b0.x, b0.y, b0.z, b0.w, b1.x, b1.y, b1.z, b1.w};
#pragma unroll
            for (int r = 0; r < 4; ++r) {
                float av = ar[r][kk];
#pragma unroll
                for (int j = 0; j < 8; ++j) acc[r][j] = fmaf(av, bv[j], acc[r][j]);
            }
        }
    }
}

// ---- K1: pre = node_features @ bcat; cols 0..511 -> bf16, 512..639 -> f32 ----
__global__ __launch_bounds__(256) void k_node_pre(const float* __restrict__ nf,
                                                  const float* __restrict__ bcat,
                                                  u16* __restrict__ pre16,
                                                  float* __restrict__ premsg) {
    __shared__ float Al[64 * 128];
    __shared__ float Bl[64 * 128];
    int t = threadIdx.x, n0 = blockIdx.x * 64;
    int trow = t >> 4, tcol = t & 15;
#pragma unroll
    for (int q = 0; q < 8; ++q) {
        int g = t + 256 * q;
        int i = g >> 5, k4 = (g & 31) * 4;
        int n = n0 + i;
        float4 v = make_float4(0.f, 0.f, 0.f, 0.f);
        if (n < 25000) v = *(const float4*)&nf[(size_t)n * 128 + k4];
        *(float4*)&Al[i * 128 + k4] = v;
    }
    for (int cc = 0; cc < 5; ++cc) {
        float acc[4][8] = {};
        for (int kh = 0; kh < 2; ++kh) {
            __syncthreads();
#pragma unroll
            for (int q = 0; q < 8; ++q) {
                int g = t + 256 * q;
                int k = g >> 5, c4 = (g & 31) * 4;
                *(float4*)&Bl[k * 128 + c4] =
                    *(const float4*)&bcat[(kh * 64 + k) * 640 + cc * 128 + c4];
            }
            __syncthreads();
            gemm_tile(Al, 128, kh * 64, Bl, trow, tcol, acc);
        }
#pragma unroll
        for (int r = 0; r < 4; ++r) {
            int n = n0 + trow * 4 + r;
            if (n < 25000) {
                if (cc < 4) {
                    u16x8 h8;
#pragma unroll
                    for (int j = 0; j < 8; ++j) h8[j] = f2b(acc[r][j]);
                    *(u16x8*)&pre16[(size_t)n * 512 + cc * 128 + tcol * 8] = h8;
                } else {
                    *(float4*)&premsg[(size_t)n * 128 + tcol * 8] =
                        make_float4(acc[r][0], acc[r][1], acc[r][2], acc[r][3]);
                    *(float4*)&premsg[(size_t)n * 128 + tcol * 8 + 4] =
                        make_float4(acc[r][4], acc[r][5], acc[r][6], acc[r][7]);
                }
            }
        }
        __syncthreads();
    }
}

// ---- K2a: histogram of dst ----
__global__ void k_hist(const int* __restrict__ eidx, int* __restrict__ count) {
    int e = blockIdx.x * 256 + threadIdx.x;
    if (e < 400000) atomicAdd(&count[eidx[e]], 1);
}

// ---- K2b: exclusive scan (single block) count -> cursor ----
__global__ __launch_bounds__(1024) void k_scan(const int* __restrict__ count,
                                               int* __restrict__ cursor) {
    __shared__ int sums[1024];
    int t = threadIdx.x;
    int base = t * 25;
    int v[25];
    int local = 0;
#pragma unroll
    for (int i = 0; i < 25; ++i) {
        int idx = base + i;
        int c = (idx < 25000) ? count[idx] : 0;
        v[i] = local;
        local += c;
    }
    sums[t] = local;
    __syncthreads();
    for (int off = 1; off < 1024; off <<= 1) {
        int x = (t >= off) ? sums[t - off] : 0;
        __syncthreads();
        sums[t] += x;
        __syncthreads();
    }
    int prefix = (t == 0) ? 0 : sums[t - 1];
#pragma unroll
    for (int i = 0; i < 25; ++i) {
        int idx = base + i;
        if (idx < 25000) cursor[idx] = prefix + v[i];
    }
}

// ---- K2c: scatter edge ids + dst/src into dst-sorted order ----
__global__ void k_scatter(const int* __restrict__ eidx, int* __restrict__ cursor,
                          int* __restrict__ perm, int* __restrict__ dsts,
                          int* __restrict__ srcs) {
    int e = blockIdx.x * 256 + threadIdx.x;
    if (e < 400000) {
        int d = eidx[e];
        int p = atomicAdd(&cursor[d], 1);
        perm[p] = e;
        dsts[p] = d;
        srcs[p] = eidx[400000 + e];
    }
}

// ---- K3: edge logits via bf16 MFMA over dst-sorted edges + atomic max ----
__global__ __launch_bounds__(256) void k_edge_logits(
        const float* __restrict__ ef, const int* __restrict__ perm,
        const int* __restrict__ dsts, const int* __restrict__ srcs,
        const u16* __restrict__ ewfrag, const u16* __restrict__ pre16,
        const float* __restrict__ btot, const float* __restrict__ aproj,
        float* __restrict__ logits_s, unsigned* __restrict__ maxkey) {
    __shared__ int eperm[64], dstl[64], srcl[64];
    int t = threadIdx.x;
    int w = t >> 6, l = t & 63;
    int p0 = blockIdx.x * 64;
    int row = l & 15, kb = l >> 4;

    if (t < 64) {
        eperm[t] = perm[p0 + t];
        dstl[t] = dsts[p0 + t];
        srcl[t] = srcs[p0 + t];
    }
    __syncthreads();

    // A frags: lane holds ef[perm[p0+w*16+row]][kb*8+i] (k 0..31) and +32 (k 32..63)
    int ea = eperm[w * 16 + row];
    const float* ap = &ef[(size_t)ea * 64 + kb * 8];
    float4 a00 = *(const float4*)ap;
    float4 a01 = *(const float4*)(ap + 4);
    float4 a10 = *(const float4*)(ap + 32);
    float4 a11 = *(const float4*)(ap + 36);
    bf8 a0 = pack8(a00, a01), a1 = pack8(a10, a11);

    // epilogue rows: C row = kb*4 + r
    int ed[4], es[4];
#pragma unroll
    for (int r = 0; r < 4; ++r) {
        int i4 = w * 16 + kb * 4 + r;
        ed[r] = dstl[i4];
        es[r] = srcl[i4];
    }

    float part0[4] = {0.f, 0.f, 0.f, 0.f}, part1[4] = {0.f, 0.f, 0.f, 0.f};
#pragma unroll
    for (int c = 0; c < 16; ++c) {
        bf8 b0 = *(const bf8*)&ewfrag[(size_t)((c * 2 + 0) * 64 + l) * 8];
        bf8 b1 = *(const bf8*)&ewfrag[(size_t)((c * 2 + 1) * 64 + l) * 8];
        f4 acc = {0.f, 0.f, 0.f, 0.f};
        acc = __builtin_amdgcn_mfma_f32_16x16x32_bf16(a0, b0, acc, 0, 0, 0);
        acc = __builtin_amdgcn_mfma_f32_16x16x32_bf16(a1, b1, acc, 0, 0, 0);
        int col = c * 16 + row;             // C col = lane&15
        float bt = btot[col], apj = aproj[col];
#pragma unroll
        for (int r = 0; r < 4; ++r) {
            float pi = b2f(pre16[(size_t)ed[r] * 512 + col]);
            float pj = b2f(pre16[(size_t)es[r] * 512 + 256 + col]);
            float hid = acc[r] + pi + pj + bt;
            hid = hid >= 0.f ? hid : NEG * hid;
            if (c < 8) part0[r] = fmaf(hid, apj, part0[r]);
            else       part1[r] = fmaf(hid, apj, part1[r]);
        }
    }
    // reduce over the 16 col-lanes (low 4 lane bits)
#pragma unroll
    for (int m = 1; m < 16; m <<= 1) {
#pragma unroll
        for (int r = 0; r < 4; ++r) {
            part0[r] += __shfl_xor(part0[r], m);
            part1[r] += __shfl_xor(part1[r], m);
        }
    }
    if (row == 0) {
#pragma unroll
        for (int r = 0; r < 4; ++r) {
            int p = p0 + w * 16 + kb * 4 + r;
            logits_s[(size_t)p * 2 + 0] = part0[r];
            logits_s[(size_t)p * 2 + 1] = part1[r];
            atomicMax(&maxkey[ed[r] * 2 + 0], fkey(part0[r]));
            atomicMax(&maxkey[ed[r] * 2 + 1], fkey(part1[r]));
        }
    }
}

// ---- K4: ex = exp(logit - max); denom += ex  (sorted space) ----
__global__ void k_soft(const int* __restrict__ dsts, float* __restrict__ logits_s,
                       const unsigned* __restrict__ maxkey, float* __restrict__ denom) {
    int idx = blockIdx.x * 256 + threadIdx.x;
    if (idx >= 800000) return;
    int p = idx >> 1, h = idx & 1;
    int d = dsts[p];
    float m = keyf(maxkey[d * 2 + h]);
    float ex = __expf(logits_s[idx] - m);
    logits_s[idx] = ex;
    atomicAdd(&denom[d * 2 + h], ex);
}

// ---- K5: messages via bf16 MFMA over dst-sorted edges + segmented reduce ----
__global__ __launch_bounds__(256) void k_messages(
        const float* __restrict__ ef, const int* __restrict__ perm,
        const int* __restrict__ dsts, const int* __restrict__ srcs,
        const u16* __restrict__ msgfrag, const float* __restrict__ premsg,
        const float* __restrict__ exs, const float* __restrict__ denom,
        float* __restrict__ agg) {
    __shared__ float Msg[64 * 132];
    __shared__ int dstl[64], srcl[64], eperm[64];
    __shared__ float attl[64][2];
    int t = threadIdx.x;
    int w = t >> 6, l = t & 63;
    int p0 = blockIdx.x * 64;
    int row = l & 15, kb = l >> 4;

    if (t < 64) {
        int p = p0 + t;
        eperm[t] = perm[p];
        int d = dsts[p];
        dstl[t] = d;
        srcl[t] = srcs[p];
        attl[t][0] = exs[(size_t)p * 2 + 0] / denom[d * 2 + 0];
        attl[t][1] = exs[(size_t)p * 2 + 1] / denom[d * 2 + 1];
    }
    __syncthreads();

    int ea = eperm[w * 16 + row];
    const float* apr = &ef[(size_t)ea * 64 + kb * 8];
    float4 a00 = *(const float4*)apr;
    float4 a01 = *(const float4*)(apr + 4);
    float4 a10 = *(const float4*)(apr + 32);
    float4 a11 = *(const float4*)(apr + 36);
    bf8 a0 = pack8(a00, a01), a1 = pack8(a10, a11);

    int esr[4];
    float at0[4], at1[4];
#pragma unroll
    for (int r = 0; r < 4; ++r) {
        int i4 = w * 16 + kb * 4 + r;
        esr[r] = srcl[i4];
        at0[r] = attl[i4][0];
        at1[r] = attl[i4][1];
    }

#pragma unroll
    for (int c = 0; c < 8; ++c) {
        bf8 b0 = *(const bf8*)&msgfrag[(size_t)((c * 2 + 0) * 64 + l) * 8];
        bf8 b1 = *(const bf8*)&msgfrag[(size_t)((c * 2 + 1) * 64 + l) * 8];
        f4 acc = {0.f, 0.f, 0.f, 0.f};
        acc = __builtin_amdgcn_mfma_f32_16x16x32_bf16(a0, b0, acc, 0, 0, 0);
        acc = __builtin_amdgcn_mfma_f32_16x16x32_bf16(a1, b1, acc, 0, 0, 0);
        int col = c * 16 + row;             // msg col 0..127; head = c>>2
#pragma unroll
        for (int r = 0; r < 4; ++r) {
            float m = acc[r] + premsg[(size_t)esr[r] * 128 + col];
            float wm = ((c < 4) ? at0[r] : at1[r]) * m;
            Msg[(w * 16 + kb * 4 + r) * 132 + col] = wm;
        }
    }
    __syncthreads();

    // segmented reduction over sorted dst; one atomic per (run, col)
    int c = t & 127, half = t >> 7;
    int r0 = half * 32, r1 = r0 + 32;
    int cur = dstl[r0];
    float sum = 0.f;
    for (int r = r0; r < r1; ++r) {
        int d = dstl[r];
        if (d != cur) {
            atomicAdd(&agg[(size_t)cur * 128 + c], sum);
            sum = 0.f;
            cur = d;
        }
        sum += Msg[r * 132 + c];
    }
    atomicAdd(&agg[(size_t)cur * 128 + c], sum);
}

// ---- K6: out = (agg + msg_b*[has_edges]) @ out_W + out_b ----
__global__ __launch_bounds__(256) void k_out(
        const float* __restrict__ agg, const float* __restrict__ denom,
        const float* __restrict__ msgb, const float* __restrict__ outW,
        const float* __restrict__ outb, float* __restrict__ out) {
    __shared__ float Al[64 * 128];
    __shared__ float Bl[64 * 128];
    int t = threadIdx.x, n0 = blockIdx.x * 64;
    int trow = t >> 4, tcol = t & 15;
#pragma unroll
    for (int q = 0; q < 8; ++q) {
        int g = t + 256 * q;
        int i = g >> 5, k4 = (g & 31) * 4;
        int n = n0 + i;
        float4 v = make_float4(0.f, 0.f, 0.f, 0.f);
        if (n < 25000) {
            v = *(const float4*)&agg[(size_t)n * 128 + k4];
            if (denom[n * 2 + (k4 >> 6)] > 0.f) {
                float4 mb = *(const float4*)&msgb[k4];
                v.x += mb.x; v.y += mb.y; v.z += mb.z; v.w += mb.w;
            }
        }
        *(float4*)&Al[i * 128 + k4] = v;
    }
    float acc[4][8] = {};
    for (int kh = 0; kh < 2; ++kh) {
        __syncthreads();
#pragma unroll
        for (int q = 0; q < 8; ++q) {
            int g = t + 256 * q;
            int k = g >> 5, c4 = (g & 31) * 4;
            *(float4*)&Bl[k * 128 + c4] = *(const float4*)&outW[(kh * 64 + k) * 128 + c4];
        }
        __syncthreads();
        gemm_tile(Al, 128, kh * 64, Bl, trow, tcol, acc);
    }
    float ob[8];
    *(float4*)ob = *(const float4*)&outb[tcol * 8];
    *(float4*)(ob + 4) = *(const float4*)&outb[tcol * 8 + 4];
#pragma unroll
    for (int r = 0; r < 4; ++r) {
        int n = n0 + trow * 4 + r;
        if (n < 25000) {
            *(float4*)&out[(size_t)n * 128 + tcol * 8] =
                make_float4(acc[r][0] + ob[0], acc[r][1] + ob[1], acc[r][2] + ob[2], acc[r][3] + ob[3]);
            *(float4*)&out[(size_t)n * 128 + tcol * 8 + 4] =
                make_float4(acc[r][4] + ob[4], acc[r][5] + ob[5], acc[r][6] + ob[6], acc[r][7] + ob[7]);
        }
    }
}

extern "C" void kernel_launch(void* const* d_in, const int* in_sizes, int n_in,
                              void* d_out, int out_size, void* d_ws, size_t ws_size,
                              hipStream_t stream) {
    const float* nf    = (const float*)d_in[0];
    const float* ef    = (const float*)d_in[1];
    const int*   eidx  = (const int*)d_in[2];
    const float* niW   = (const float*)d_in[3];
    const float* nib   = (const float*)d_in[4];
    const float* njW   = (const float*)d_in[5];
    const float* njb   = (const float*)d_in[6];
    const float* eW    = (const float*)d_in[7];
    const float* eb    = (const float*)d_in[8];
    const float* aproj = (const float*)d_in[9];
    const float* msgW  = (const float*)d_in[10];
    const float* msgb  = (const float*)d_in[11];
    const float* outW  = (const float*)d_in[12];
    const float* outb  = (const float*)d_in[13];

    float* ws = (float*)d_ws;
    float* premsg    = ws + OFF_PREM;
    u16*   pre16     = (u16*)(ws + OFF_P16);
    float* bcat      = ws + OFF_BCAT;
    float* btot      = ws + OFF_BTOT;
    float* logits_s  = ws + OFF_LOG;
    unsigned* maxkey = (unsigned*)(ws + OFF_MAX);
    float* denom     = ws + OFF_DEN;
    float* agg       = ws + OFF_AGG;
    int*   count     = (int*)(ws + OFF_CNT);
    int*   cursor    = (int*)(ws + OFF_CUR);
    int*   perm      = (int*)(ws + OFF_PERM);
    int*   dsts      = (int*)(ws + OFF_DST);
    int*   srcs      = (int*)(ws + OFF_SRC);
    u16*   ewfrag    = (u16*)(ws + OFF_EWF);
    u16*   msgfrag   = (u16*)(ws + OFF_MWF);

    // zero maxkey + denom + agg + count (contiguous)
    hipMemsetAsync(ws + OFF_MAX, 0, (size_t)(SZ_MAX + SZ_DEN + SZ_AGG + SZ_CNT) * 4, stream);

    k_prep<<<320, 256, 0, stream>>>(niW, njW, msgW, eW, nib, njb, eb, bcat, btot, ewfrag, msgfrag);
    k_node_pre<<<391, 256, 0, stream>>>(nf, bcat, pre16, premsg);
    k_hist<<<1563, 256, 0, stream>>>(eidx, count);
    k_scan<<<1, 1024, 0, stream>>>(count, cursor);
    k_scatter<<<1563, 256, 0, stream>>>(eidx, cursor, perm, dsts, srcs);
    k_edge_logits<<<6250, 256, 0, stream>>>(ef, perm, dsts, srcs, ewfrag, pre16, btot, aproj, logits_s, maxkey);
    k_soft<<<3125, 256, 0, stream>>>(dsts, logits_s, maxkey, denom);
    k_messages<<<6250, 256, 0, stream>>>(ef, perm, dsts, srcs, msgfrag, premsg, logits_s, denom, agg);
    k_out<<<391, 256, 0, stream>>>(agg, denom, msgb, outW, outb, (float*)d_out);
}